// Round 6
// baseline (1336.115 us; speedup 1.0000x reference)
//
#include <hip/hip_runtime.h>

// SNN layer: currents[t,b,o] = sum_i x[b,i,t] * w[i,o] in fp64 (binary spike output
// demands decision-exactness vs the numpy fp64 ref), then sequential LIF scan.
//
// Round 6:
//  - LDS rows padded to 136 floats (136 % 32 == 8). Rounds 4/5 had identical
//    SQ_LDS_BANK_CONFLICT = 3.355e7: the 4 kq quads read rows kk..kk+3 whose
//    stride (128) is 0 mod 32 banks -> 4-way same-bank conflicts on every
//    fragment read. Stride 136 puts the quads 8 banks apart -> 2 lanes/bank = free.
//  - Scan writes via LDS transpose: old path wrote 16B/lane at 4000B lane stride
//    (uncoalesced, ~4x amplification). Now 64t x 64row tile in LDS, flushed with
//    lane-along-t coalesced 256B row stores.
//  - f64 MFMA D-layout probe kept from rounds 4/5 (decodes the register->row/col
//    mapping at runtime from an exact integer identity product).
//
// ws layout: [0, 256KB)   : v-state, 32*1024 doubles (carried across T-chunks)
//            [256KB, ...) : current chunk buffer, Tc * 32 * 1024 doubles

#define NB 32
#define NI 1024
#define NO 1024
#define NT 1000
#define TT 128   // t-tile per block
#define OT 128   // o-tile per block
#define KI 16    // k (i) tile
#define LP 8     // LDS row pad: stride 136 = 8 mod 32 banks

typedef double d4 __attribute__((ext_vector_type(4)));

__global__ __launch_bounds__(256, 3)
void snn_gemm_mfma64(const float* __restrict__ x, const float* __restrict__ w,
                     double* __restrict__ cur, int t0, int len)
{
    __shared__ float As[KI][TT + LP];   // 8.5 KB (i-major, t contiguous)
    __shared__ float Bs[KI][OT + LP];   // 8.5 KB (i-major, o contiguous)

    const int tid  = threadIdx.x;
    const int lane = tid & 63;
    const int wave = tid >> 6;           // 4 waves: 2x2 grid of 64x64 wave tiles
    const int wm   = (wave >> 1) * 64;   // t offset within block tile
    const int wn   = (wave & 1) * 64;    // o offset within block tile
    const int m16  = lane & 15;
    const int kq   = lane >> 4;          // 0..3

    const int tt0 = t0 + blockIdx.x * TT;
    const int o0  = blockIdx.y * OT;
    const int b   = blockIdx.z;
    const float* xb = x + (size_t)b * NI * NT;

    // ---- probe the D register->element mapping of v_mfma_f64_16x16x4f64 ----
    // A = identity (4 K-slices), B[k][n] = 100k+n+1  =>  D[m][n] = 100m+n+1.
    // Exact small integers in fp64 -> each lane decodes (row,col) per acc register.
    d4 p = (d4)0.0;
#pragma unroll
    for (int s = 0; s < 4; ++s) {
        const double ap = (m16 == kq + 4 * s) ? 1.0 : 0.0;        // A[m=lane&15][k=lane>>4]
        const double bp = (double)(100 * (kq + 4 * s) + m16 + 1); // B[k=lane>>4][n=lane&15]
        p = __builtin_amdgcn_mfma_f64_16x16x4f64(ap, bp, p, 0, 0, 0);
    }
    int prow[4], pcol[4];
#pragma unroll
    for (int r = 0; r < 4; ++r) {
        const int val = ((int)p[r] - 1) & 0xffff;  // 100*m + n
        const int m = val / 100;
        prow[r] = m & 15;
        pcol[r] = (val - m * 100) & 15;
    }

    d4 acc[4][4];   // [t-tile][o-tile] -> AGPRs
#pragma unroll
    for (int r = 0; r < 4; ++r)
#pragma unroll
        for (int c = 0; c < 4; ++c) acc[r][c] = (d4)0.0;

    // staging: 16 rows x 128 cols per matrix, 2 float4 per thread per matrix
    const int sr = tid >> 5;         // rows sr and sr+8
    const int sc = (tid & 31) * 4;   // 0,4,...,124
    const int at = tt0 + sc;

    for (int i0 = 0; i0 < NI; i0 += KI) {
        float4 a0 = make_float4(0.f, 0.f, 0.f, 0.f);
        float4 a1 = a0;
        if (at < NT) {   // NT%4==0, at%4==0 -> whole float4 in bounds when at<NT
            a0 = *(const float4*)(xb + (size_t)(i0 + sr) * NT + at);
            a1 = *(const float4*)(xb + (size_t)(i0 + sr + 8) * NT + at);
        }
        const float4 b0 = *(const float4*)(w + (size_t)(i0 + sr) * NO + (o0 + sc));
        const float4 b1 = *(const float4*)(w + (size_t)(i0 + sr + 8) * NO + (o0 + sc));

        __syncthreads();   // previous iteration's LDS reads done
        *(float4*)&As[sr][sc]     = a0;
        *(float4*)&As[sr + 8][sc] = a1;
        *(float4*)&Bs[sr][sc]     = b0;
        *(float4*)&Bs[sr + 8][sc] = b1;
        __syncthreads();

#pragma unroll
        for (int k4 = 0; k4 < 4; ++k4) {
            const int kk = k4 * 4 + kq;
            double af[4], bf[4];
#pragma unroll
            for (int r = 0; r < 4; ++r) af[r] = (double)As[kk][wm + r * 16 + m16];
#pragma unroll
            for (int c = 0; c < 4; ++c) bf[c] = (double)Bs[kk][wn + c * 16 + m16];
#pragma unroll
            for (int r = 0; r < 4; ++r)
#pragma unroll
                for (int c = 0; c < 4; ++c)
                    acc[r][c] = __builtin_amdgcn_mfma_f64_16x16x4f64(
                        af[r], bf[c], acc[r][c], 0, 0, 0);
        }
    }

    // store via probed mapping: acc[rt][ct][j] holds D_tile[prow[j]][pcol[j]]
    const int tend = t0 + len;
#pragma unroll
    for (int rt = 0; rt < 4; ++rt) {
#pragma unroll
        for (int j = 0; j < 4; ++j) {
            const int tg = tt0 + wm + rt * 16 + prow[j];
            if (tg < tend) {
                double* dst = cur + ((size_t)(tg - t0) * NB + b) * NO + o0 + wn;
#pragma unroll
                for (int ct = 0; ct < 4; ++ct)
                    dst[ct * 16 + pcol[j]] = acc[rt][ct][j];
            }
        }
    }
}

// LIF scan: one thread per (b,o); cur chunk is [tc][b*NO+o] fp64 (coalesced reads:
// 64 lanes x 8B contiguous). Output is [b*NO+o][t] fp32 -> buffer 64 t-steps in an
// LDS tile and flush transposed so stores are lane-along-t coalesced.
__global__ __launch_bounds__(64)
void snn_scan_f64(const double* __restrict__ cur, float* __restrict__ out,
                  double* __restrict__ vstate, int t0, int len)
{
    __shared__ float tile[64][65];                   // [row][t_local], 65: bank-safe
    const int tid   = threadIdx.x;
    const int gbase = blockIdx.x * 64;
    const int gid   = gbase + tid;                   // b*NO + o
    const double dt = 0.001 / 50.0;                  // MS / TAU, IEEE double

    double v = (t0 == 0) ? 0.0 : vstate[gid];
    const double* cp = cur + gid;                    // stride NB*NO per t-step
    const size_t ts = (size_t)NB * NO;               // 32768
    const int ng = len >> 3;                         // len always multiple of 8

    double c[8], n[8];
#pragma unroll
    for (int j = 0; j < 8; ++j) c[j] = cp[(size_t)j * ts];
#pragma unroll
    for (int j = 0; j < 8; ++j) n[j] = (ng > 1) ? cp[(size_t)(8 + j) * ts] : 0.0;

    for (int g = 0; g < ng; ++g) {
        double m[8];
        if (g + 2 < ng) {
            const double* q = cp + (size_t)(8 * (g + 2)) * ts;
#pragma unroll
            for (int j = 0; j < 8; ++j) m[j] = q[(size_t)j * ts];
        } else {
#pragma unroll
            for (int j = 0; j < 8; ++j) m[j] = 0.0;
        }
        const int tl = (g & 7) * 8;                  // t_local of this group
#pragma unroll
        for (int j = 0; j < 8; ++j) {
            v = v + (c[j] - v) * dt;
            const bool sp = (v >= 1.0);
            tile[tid][tl + j] = sp ? 1.0f : 0.0f;    // banks: tid -> all distinct
            if (sp) v = 0.0;
        }
        if ((g & 7) == 7 || g == ng - 1) {           // flush 64 (or tail) t-steps
            const int c0   = (g & ~7) * 8;           // chunk start, t_local space
            const int clen = tl + 8;                 // valid columns in tile
            __syncthreads();                         // fence LDS writes (1 wave)
            if (tid < clen) {
#pragma unroll 4
                for (int r = 0; r < 64; ++r)         // 256B coalesced per row
                    out[(size_t)(gbase + r) * NT + t0 + c0 + tid] = tile[r][tid];
            }
            __syncthreads();
        }
#pragma unroll
        for (int j = 0; j < 8; ++j) { c[j] = n[j]; n[j] = m[j]; }
    }
    vstate[gid] = v;
}

extern "C" void kernel_launch(void* const* d_in, const int* in_sizes, int n_in,
                              void* d_out, int out_size, void* d_ws, size_t ws_size,
                              hipStream_t stream)
{
    const float* x = (const float*)d_in[0];
    const float* w = (const float*)d_in[1];
    float* out = (float*)d_out;

    const size_t vbytes = (size_t)NB * NO * sizeof(double);   // 256 KB
    double* vstate = (double*)d_ws;
    double* curbuf = (double*)((char*)d_ws + vbytes);

    const size_t per_t = (size_t)NB * NO * sizeof(double);    // 256 KB per t-step
    size_t avail = (ws_size > vbytes) ? (ws_size - vbytes) : 0;
    int Tc = (int)((avail / per_t < (size_t)NT) ? (avail / per_t) : (size_t)NT);
    Tc &= ~7;                 // multiple of 8 (scan groups; 1000%8==0 so every len is too)
    if (Tc < 8) Tc = 8;

    for (int t0 = 0; t0 < NT; t0 += Tc) {
        const int len = (NT - t0 < Tc) ? (NT - t0) : Tc;
        dim3 gg((len + TT - 1) / TT, NO / OT, NB);
        snn_gemm_mfma64<<<gg, 256, 0, stream>>>(x, w, curbuf, t0, len);
        snn_scan_f64<<<(NB * NO) / 64, 64, 0, stream>>>(curbuf, out, vstate, t0, len);
    }
}